// Round 2
// baseline (42189.413 us; speedup 1.0000x reference)
//
#include <hip/hip_runtime.h>
#include <hip/hip_cooperative_groups.h>

#define B_ 64
#define H_ 1024
#define IN_ 512
#define S_ 256
#define L_ 6
#define NG_ 4096
#define NWG 768
#define NTICK (S_ + L_ - 1)

typedef __bf16 bf16x8 __attribute__((ext_vector_type(8)));
typedef float f32x4 __attribute__((ext_vector_type(4)));
typedef float f32x2 __attribute__((ext_vector_type(2)));
typedef unsigned short ushort4v __attribute__((ext_vector_type(4)));

// weight offsets in elements (bf16) inside ws
#define OFF_U0 0ul
#define OFF_V0 2097152ul
#define OFF_UL(l) (6291456ul + (unsigned long)((l) - 1) * 8388608ul)
#define OFF_VL(l) (OFF_UL(l) + 4194304ul)
#define WT_BYTES 96468992ul
#define XB_BYTES 16777216ul
#define HBF_ELEMS 786432ul    // 2*L*B*H

__device__ __forceinline__ unsigned short f2bf(float f) {
  union { float f; unsigned u; } v; v.f = f;
  unsigned r = v.u + 0x7fffu + ((v.u >> 16) & 1u);
  return (unsigned short)(r >> 16);
}

// ---- one-time weight transpose + bf16 convert: Wt[n][k] = bf16(W[k][n]) ----
__global__ void k_transpose_bf16(const float* __restrict__ W,
                                 unsigned short* __restrict__ Wt,
                                 int K, int N) {
  __shared__ float tile[32][33];
  int n0 = blockIdx.x * 32, k0 = blockIdx.y * 32;
  int tx = threadIdx.x, ty = threadIdx.y; // 32 x 8
#pragma unroll
  for (int i = 0; i < 32; i += 8)
    tile[ty + i][tx] = W[(size_t)(k0 + ty + i) * N + (n0 + tx)];
  __syncthreads();
#pragma unroll
  for (int i = 0; i < 32; i += 8)
    Wt[(size_t)(n0 + ty + i) * K + (k0 + tx)] = f2bf(tile[tx][ty + i]);
}

// ---- one-time x -> bf16 ----
__global__ void k_cvt_bf16(const float* __restrict__ src,
                           unsigned short* __restrict__ dst, int n4) {
  int i = blockIdx.x * blockDim.x + threadIdx.x;
  if (i < n4) {
    float4 v = ((const float4*)src)[i];
    ushort4v o = { f2bf(v.x), f2bf(v.y), f2bf(v.z), f2bf(v.w) };
    ((ushort4v*)dst)[i] = o;
  }
}

// 2 M-fragments (rows r, r+16) x 16 cols, K-streamed.
__device__ __forceinline__ void gemm_acc2(f32x4 acc[2],
                                          const unsigned short* __restrict__ Ar,
                                          size_t strideA,
                                          const unsigned short* __restrict__ Br,
                                          int K) {
  const unsigned short* r0 = Ar;
  const unsigned short* r1 = Ar + 16 * strideA;
#pragma unroll 8
  for (int k = 0; k < K; k += 32) {
    bf16x8 bv = __builtin_nontemporal_load((const bf16x8*)(Br + k));
    bf16x8 a0 = *(const bf16x8*)(r0 + k);
    bf16x8 a1 = *(const bf16x8*)(r1 + k);
    acc[0] = __builtin_amdgcn_mfma_f32_16x16x32_bf16(a0, bv, acc[0], 0, 0, 0);
    acc[1] = __builtin_amdgcn_mfma_f32_16x16x32_bf16(a1, bv, acc[1], 0, 0, 0);
  }
}

__global__ void __launch_bounds__(256)
k_lstm(const unsigned short* __restrict__ xb,
       const unsigned short* __restrict__ Wt,
       const float* __restrict__ b0,
       const float* __restrict__ bL,
       unsigned short* __restrict__ hbf,   // [2][L][B][H] bf16, pre-zeroed
       float* __restrict__ out) {
  cooperative_groups::grid_group grid = cooperative_groups::this_grid();
  float* __restrict__ seq = out;                           // [B][S][H]
  float* __restrict__ hf = out + (size_t)B_ * S_ * H_;     // [L][B][H]
  float* __restrict__ cf = hf + (size_t)L_ * B_ * H_;      // [L][B][H]
  __shared__ float zs[4][32][16];

  const int tid = threadIdx.x;
  const int wave = tid >> 6;   // gate
  const int lane = tid & 63;
  const int l15 = lane & 15;
  const int kg = lane >> 4;
  const int wg = blockIdx.x;

  for (int T = 0; T < NTICK; ++T) {
    const int lmin = (T > S_ - 1) ? (T - (S_ - 1)) : 0;
    const int lmax = (T < L_ - 1) ? T : (L_ - 1);
    const int ntask = (lmax - lmin + 1) << 7;   // layers * 2 Mblocks * 64 col-slices
    const unsigned short* __restrict__ hprev =
        hbf + (size_t)((T + 1) & 1) * (L_ * B_ * H_);
    unsigned short* __restrict__ hcur =
        hbf + (size_t)(T & 1) * (L_ * B_ * H_);

    for (int task = wg; task < ntask; task += NWG) {
      const int l = lmin + (task >> 7);
      const int rem = task & 127;
      const int mb = rem >> 6;          // M-block: rows [mb*32, mb*32+32)
      const int jb = rem & 63;          // 16-col slice
      const int t = T - l;
      const int m0 = mb << 5;
      const int jcol0 = jb << 4;
      const int ngl = (wave << 10) + jcol0 + l15; // weight row (output col)

      const unsigned short* A1;
      size_t sA1;
      const unsigned short* WU;
      int K1;
      if (l == 0) {
        A1 = xb + (size_t)t * IN_;  // row b at + b*S*IN
        sA1 = (size_t)S_ * IN_;
        WU = Wt + OFF_U0;
        K1 = IN_;
      } else {
        A1 = hprev + (size_t)(l - 1) * (B_ * H_);
        sA1 = H_;
        WU = Wt + OFF_UL(l);
        K1 = H_;
      }
      const unsigned short* A2 = hprev + (size_t)l * (B_ * H_);
      const unsigned short* WV = Wt + ((l == 0) ? OFF_V0 : OFF_VL(l));

      f32x4 acc[2];
      acc[0] = (f32x4){0.f, 0.f, 0.f, 0.f};
      acc[1] = (f32x4){0.f, 0.f, 0.f, 0.f};

      gemm_acc2(acc, A1 + (size_t)(m0 + l15) * sA1 + kg * 8, sA1,
                WU + (size_t)ngl * K1 + kg * 8, K1);
      gemm_acc2(acc, A2 + (size_t)(m0 + l15) * H_ + kg * 8, H_,
                WV + (size_t)ngl * H_ + kg * 8, H_);

      // D layout: col = lane&15, row = (lane>>4)*4 + j  (within each 16-row frag)
#pragma unroll
      for (int mf = 0; mf < 2; ++mf)
#pragma unroll
        for (int j = 0; j < 4; ++j)
          zs[wave][mf * 16 + kg * 4 + j][l15] = acc[mf][j];
      __syncthreads();

      // ---- gate phase: 256 threads cover 32 rows x 16 cols, 2 each ----
      {
        const float* __restrict__ bias = (l == 0) ? b0 : (bL + (size_t)(l - 1) * NG_);
        const int m = tid >> 3;            // 0..31 row within block
        const int nq = (tid & 7) << 1;     // 0..14 col pair
        const int col = jcol0 + nq;
        const int row = m0 + m;
        f32x2 zi = *(const f32x2*)&zs[0][m][nq] + *(const f32x2*)(bias + col);
        f32x2 zf = *(const f32x2*)&zs[1][m][nq] + *(const f32x2*)(bias + 1024 + col);
        f32x2 zg = *(const f32x2*)&zs[2][m][nq] + *(const f32x2*)(bias + 2048 + col);
        f32x2 zo = *(const f32x2*)&zs[3][m][nq] + *(const f32x2*)(bias + 3072 + col);
        const size_t cbase = ((size_t)l * B_ + row) * H_ + col;
        f32x2 cold;
        if (t == 0) cold = (f32x2){0.f, 0.f};
        else cold = *(const f32x2*)(cf + cbase);
        f32x2 cnew, hv;
#pragma unroll
        for (int j = 0; j < 2; ++j) {
          float iv = 1.f / (1.f + expf(-zi[j]));
          float fv = 1.f / (1.f + expf(-zf[j]));
          float gv = tanhf(zg[j]);
          float ov = 1.f / (1.f + expf(-zo[j]));
          float cn = fv * cold[j] + iv * gv;
          cnew[j] = cn;
          hv[j] = ov * tanhf(cn);
        }
        *(f32x2*)(cf + cbase) = cnew;
        *(f32x2*)(hf + cbase) = hv;
        unsigned hb2 = (unsigned)f2bf(hv[0]) | ((unsigned)f2bf(hv[1]) << 16);
        *(unsigned*)(hcur + (size_t)l * (B_ * H_) + (size_t)row * H_ + col) = hb2;
        if (l == L_ - 1)
          *(f32x2*)(seq + ((size_t)row * S_ + t) * H_ + col) = hv;
      }
      __syncthreads(); // protect zs before reuse
    }
    grid.sync();
  }
}

extern "C" void kernel_launch(void* const* d_in, const int* in_sizes, int n_in,
                              void* d_out, int out_size, void* d_ws, size_t ws_size,
                              hipStream_t stream) {
  const float* x = (const float*)d_in[0];
  const float* U0 = (const float*)d_in[1];
  const float* V0 = (const float*)d_in[2];
  const float* b0 = (const float*)d_in[3];
  const float* U = (const float*)d_in[4];
  const float* V = (const float*)d_in[5];
  const float* bL = (const float*)d_in[6];
  float* out = (float*)d_out;

  char* ws = (char*)d_ws;
  unsigned short* Wt = (unsigned short*)ws;
  unsigned short* xb = (unsigned short*)(ws + WT_BYTES);
  unsigned short* hbf = (unsigned short*)(ws + WT_BYTES + XB_BYTES);

  dim3 tb(32, 8);
  hipLaunchKernelGGL(k_transpose_bf16, dim3(128, 16), tb, 0, stream, U0, Wt + OFF_U0, 512, 4096);
  hipLaunchKernelGGL(k_transpose_bf16, dim3(128, 32), tb, 0, stream, V0, Wt + OFF_V0, 1024, 4096);
  for (int l = 1; l < 6; ++l) {
    hipLaunchKernelGGL(k_transpose_bf16, dim3(128, 32), tb, 0, stream,
                       U + (size_t)(l - 1) * 4194304ul, Wt + OFF_UL(l), 1024, 4096);
    hipLaunchKernelGGL(k_transpose_bf16, dim3(128, 32), tb, 0, stream,
                       V + (size_t)(l - 1) * 4194304ul, Wt + OFF_VL(l), 1024, 4096);
  }
  int n4 = (B_ * S_ * IN_) / 4;
  hipLaunchKernelGGL(k_cvt_bf16, dim3((n4 + 255) / 256), dim3(256), 0, stream, x, xb, n4);
  hipMemsetAsync(hbf, 0, HBF_ELEMS * 2, stream);

  void* args[] = { (void*)&xb, (void*)&Wt, (void*)&b0, (void*)&bL, (void*)&hbf, (void*)&out };
  hipLaunchCooperativeKernel((void*)k_lstm, dim3(NWG), dim3(256), args, 0, stream);
}

// Round 4
// 33164.529 us; speedup vs baseline: 1.2721x; 1.2721x over previous
//
#include <hip/hip_runtime.h>
#include <hip/hip_cooperative_groups.h>

#define B_ 64
#define H_ 1024
#define IN_ 512
#define S_ 256
#define L_ 6
#define NG_ 4096
#define NTASK 768            // 6 layers * 128 col-slices (8 H-cols x 4 gates each)
#define NTICK (S_ + L_ - 1)

typedef __bf16 bf16x8 __attribute__((ext_vector_type(8)));
typedef float f32x4 __attribute__((ext_vector_type(4)));
typedef float f32x2 __attribute__((ext_vector_type(2)));
typedef unsigned short ushort4v __attribute__((ext_vector_type(4)));
typedef unsigned short ushort_t;

// weight offsets in bf16 elements inside ws
#define OFF_U0 0ul
#define OFF_V0 2097152ul
#define OFF_UL(l) (6291456ul + (unsigned long)((l) - 1) * 8388608ul)
#define OFF_VL(l) (OFF_UL(l) + 4194304ul)
#define WT_BYTES 96468992ul
#define XB_BYTES 16777216ul
#define HBF_ELEMS 786432ul    // 2*L*B*H

__device__ __forceinline__ unsigned short f2bf(float f) {
  union { float f; unsigned u; } v; v.f = f;
  unsigned r = v.u + 0x7fffu + ((v.u >> 16) & 1u);
  return (unsigned short)(r >> 16);
}

// ---- one-time weight transpose + bf16 convert: Wt[n][k] = bf16(W[k][n]) ----
__global__ void k_transpose_bf16(const float* __restrict__ W,
                                 unsigned short* __restrict__ Wt,
                                 int K, int N) {
  __shared__ float tile[32][33];
  int n0 = blockIdx.x * 32, k0 = blockIdx.y * 32;
  int tx = threadIdx.x, ty = threadIdx.y; // 32 x 8
#pragma unroll
  for (int i = 0; i < 32; i += 8)
    tile[ty + i][tx] = W[(size_t)(k0 + ty + i) * N + (n0 + tx)];
  __syncthreads();
#pragma unroll
  for (int i = 0; i < 32; i += 8)
    Wt[(size_t)(n0 + ty + i) * K + (k0 + tx)] = f2bf(tile[tx][ty + i]);
}

// ---- one-time x -> bf16, layout [S][B][IN] (rows contiguous per timestep) ----
__global__ void k_cvt_x(const float* __restrict__ x, ushort_t* __restrict__ xb) {
  int t = blockIdx.x, b = blockIdx.y, k = threadIdx.x * 4;
  float4 v = *(const float4*)(x + ((size_t)b * S_ + t) * IN_ + k);
  ushort4v o = { f2bf(v.x), f2bf(v.y), f2bf(v.z), f2bf(v.w) };
  *(ushort4v*)(xb + ((size_t)t * B_ + b) * IN_ + k) = o;
}

#define MFMA16(a, b, c) __builtin_amdgcn_mfma_f32_16x16x32_bf16(a, b, c, 0, 0, 0)

// Wave GEMM: 16 rows x 32 cols, K = KITER*64. Ping-pong 2-k-step banks,
// all indices static (full unroll), compiler emits counted waitcnts.
template<int KITER>
__device__ __forceinline__ void gemm16(f32x4 acc[2],
                                       const ushort_t* __restrict__ pa,
                                       const ushort_t* __restrict__ pw0,
                                       const ushort_t* __restrict__ pw1) {
  bf16x8 Pa[2], Pw0[2], Pw1[2], Qa[2], Qw0[2], Qw1[2];
#pragma unroll
  for (int s = 0; s < 2; ++s) {
    Pa[s]  = *(const bf16x8*)(pa  + s * 32);
    Pw0[s] = *(const bf16x8*)(pw0 + s * 32);
    Pw1[s] = *(const bf16x8*)(pw1 + s * 32);
  }
#pragma unroll
  for (int it = 0; it < KITER; ++it) {
    const int kn = (it + 1) * 64;
    if ((it & 1) == 0) {
      if (it + 1 < KITER) {
#pragma unroll
        for (int s = 0; s < 2; ++s) {
          Qa[s]  = *(const bf16x8*)(pa  + kn + s * 32);
          Qw0[s] = *(const bf16x8*)(pw0 + kn + s * 32);
          Qw1[s] = *(const bf16x8*)(pw1 + kn + s * 32);
        }
      }
#pragma unroll
      for (int s = 0; s < 2; ++s) {
        acc[0] = MFMA16(Pa[s], Pw0[s], acc[0]);
        acc[1] = MFMA16(Pa[s], Pw1[s], acc[1]);
      }
    } else {
      if (it + 1 < KITER) {
#pragma unroll
        for (int s = 0; s < 2; ++s) {
          Pa[s]  = *(const bf16x8*)(pa  + kn + s * 32);
          Pw0[s] = *(const bf16x8*)(pw0 + kn + s * 32);
          Pw1[s] = *(const bf16x8*)(pw1 + kn + s * 32);
        }
      }
#pragma unroll
      for (int s = 0; s < 2; ++s) {
        acc[0] = MFMA16(Qa[s], Qw0[s], acc[0]);
        acc[1] = MFMA16(Qa[s], Qw1[s], acc[1]);
      }
    }
  }
}

__global__ void __launch_bounds__(256)
k_lstm(const ushort_t* __restrict__ xb,
       const ushort_t* __restrict__ Wt,
       const float* __restrict__ b0,
       const float* __restrict__ bL,
       ushort_t* __restrict__ hbf,   // [2][L][B][H] bf16, pre-zeroed
       float* __restrict__ out) {
  cooperative_groups::grid_group grid = cooperative_groups::this_grid();
  float* __restrict__ seq = out;                           // [B][S][H]
  float* __restrict__ hf = out + (size_t)B_ * S_ * H_;     // [L][B][H]
  float* __restrict__ cf = hf + (size_t)L_ * B_ * H_;      // [L][B][H]
  __shared__ float zs[4][64][10];   // [gate][row][8 cols + pad2]

  const int tid = threadIdx.x;
  const int w = tid >> 6;        // wave: rows w*16..w*16+15
  const int lane = tid & 63;
  const int l15 = lane & 15;
  const int kg = lane >> 4;
  const int koff = kg << 3;
  const int wg = blockIdx.x;
  const int nwg = gridDim.x;

  for (int T = 0; T < NTICK; ++T) {
    const ushort_t* __restrict__ hprev =
        hbf + (size_t)((T + 1) & 1) * (L_ * B_ * H_);
    ushort_t* __restrict__ hcur =
        hbf + (size_t)(T & 1) * (L_ * B_ * H_);

    for (int task = wg; task < NTASK; task += nwg) {
      const int l = task >> 7;
      const int jb = task & 127;
      const int t = T - l;
      if (t < 0 || t >= S_) continue;

      const int hcol0 = jb << 3;
      // weight rows (output cols) for this lane's two 16-col fragments:
      // c = nf*16 + l15 -> gate = nf*2 + (l15>>3), hcol = hcol0 + (l15&7)
      const int nrow0 = ((l15 >> 3)) * 1024 + hcol0 + (l15 & 7);
      const int nrow1 = (2 + (l15 >> 3)) * 1024 + hcol0 + (l15 & 7);
      const int arow = (w << 4) + l15;

      f32x4 acc[2];
      acc[0] = (f32x4){0.f, 0.f, 0.f, 0.f};
      acc[1] = (f32x4){0.f, 0.f, 0.f, 0.f};

      const ushort_t* pa2 = hprev + (size_t)l * (B_ * H_) + (size_t)arow * H_ + koff;
      if (l == 0) {
        const ushort_t* pa1 = xb + (size_t)t * (B_ * IN_) + (size_t)arow * IN_ + koff;
        gemm16<8>(acc, pa1,
                  Wt + OFF_U0 + (size_t)nrow0 * IN_ + koff,
                  Wt + OFF_U0 + (size_t)nrow1 * IN_ + koff);
        gemm16<16>(acc, pa2,
                   Wt + OFF_V0 + (size_t)nrow0 * H_ + koff,
                   Wt + OFF_V0 + (size_t)nrow1 * H_ + koff);
      } else {
        const ushort_t* pa1 = hprev + (size_t)(l - 1) * (B_ * H_) + (size_t)arow * H_ + koff;
        gemm16<16>(acc, pa1,
                   Wt + OFF_UL(l) + (size_t)nrow0 * H_ + koff,
                   Wt + OFF_UL(l) + (size_t)nrow1 * H_ + koff);
        gemm16<16>(acc, pa2,
                   Wt + OFF_VL(l) + (size_t)nrow0 * H_ + koff,
                   Wt + OFF_VL(l) + (size_t)nrow1 * H_ + koff);
      }

      // D layout (verified R1): within fragment, col = l15, row = kg*4 + j
      const int g0 = l15 >> 3, c7 = l15 & 7;
#pragma unroll
      for (int nf = 0; nf < 2; ++nf)
#pragma unroll
        for (int j = 0; j < 4; ++j)
          zs[nf * 2 + g0][(w << 4) + (kg << 2) + j][c7] = acc[nf][j];
      __syncthreads();

      // ---- gate phase: 256 threads cover 64 rows x 8 cols, 2 each ----
      {
        const float* __restrict__ bias = (l == 0) ? b0 : (bL + (size_t)(l - 1) * NG_);
        const int m = tid >> 2;            // batch row 0..63
        const int nq = (tid & 3) << 1;     // col pair 0,2,4,6
        const int col = hcol0 + nq;
        f32x2 zi = *(const f32x2*)&zs[0][m][nq] + *(const f32x2*)(bias + col);
        f32x2 zf = *(const f32x2*)&zs[1][m][nq] + *(const f32x2*)(bias + 1024 + col);
        f32x2 zg = *(const f32x2*)&zs[2][m][nq] + *(const f32x2*)(bias + 2048 + col);
        f32x2 zo = *(const f32x2*)&zs[3][m][nq] + *(const f32x2*)(bias + 3072 + col);
        const size_t cbase = ((size_t)l * B_ + m) * H_ + col;
        f32x2 cold;
        if (t == 0) cold = (f32x2){0.f, 0.f};
        else cold = *(const f32x2*)(cf + cbase);
        f32x2 cnew, hv;
#pragma unroll
        for (int j = 0; j < 2; ++j) {
          float iv = 1.f / (1.f + expf(-zi[j]));
          float fv = 1.f / (1.f + expf(-zf[j]));
          float gv = tanhf(zg[j]);
          float ov = 1.f / (1.f + expf(-zo[j]));
          float cn = fv * cold[j] + iv * gv;
          cnew[j] = cn;
          hv[j] = ov * tanhf(cn);
        }
        *(f32x2*)(cf + cbase) = cnew;
        *(f32x2*)(hf + cbase) = hv;
        unsigned hb2 = (unsigned)f2bf(hv[0]) | (((unsigned)f2bf(hv[1])) << 16);
        *(unsigned*)(hcur + (size_t)l * (B_ * H_) + (size_t)m * H_ + col) = hb2;
        if (l == L_ - 1)
          *(f32x2*)(seq + ((size_t)m * S_ + t) * H_ + col) = hv;
      }
      __syncthreads(); // zs safe before next task
    }
    grid.sync();
  }
}

extern "C" void kernel_launch(void* const* d_in, const int* in_sizes, int n_in,
                              void* d_out, int out_size, void* d_ws, size_t ws_size,
                              hipStream_t stream) {
  const float* x = (const float*)d_in[0];
  const float* U0 = (const float*)d_in[1];
  const float* V0 = (const float*)d_in[2];
  const float* b0 = (const float*)d_in[3];
  const float* U = (const float*)d_in[4];
  const float* V = (const float*)d_in[5];
  const float* bL = (const float*)d_in[6];
  float* out = (float*)d_out;

  char* ws = (char*)d_ws;
  unsigned short* Wt = (unsigned short*)ws;
  unsigned short* xb = (unsigned short*)(ws + WT_BYTES);
  unsigned short* hbf = (unsigned short*)(ws + WT_BYTES + XB_BYTES);

  dim3 tb(32, 8);
  hipLaunchKernelGGL(k_transpose_bf16, dim3(128, 16), tb, 0, stream, U0, Wt + OFF_U0, 512, 4096);
  hipLaunchKernelGGL(k_transpose_bf16, dim3(128, 32), tb, 0, stream, V0, Wt + OFF_V0, 1024, 4096);
  for (int l = 1; l < 6; ++l) {
    hipLaunchKernelGGL(k_transpose_bf16, dim3(128, 32), tb, 0, stream,
                       U + (size_t)(l - 1) * 4194304ul, Wt + OFF_UL(l), 1024, 4096);
    hipLaunchKernelGGL(k_transpose_bf16, dim3(128, 32), tb, 0, stream,
                       V + (size_t)(l - 1) * 4194304ul, Wt + OFF_VL(l), 1024, 4096);
  }
  hipLaunchKernelGGL(k_cvt_x, dim3(S_, B_), dim3(128), 0, stream, x, xb);
  hipMemsetAsync(hbf, 0, HBF_ELEMS * 2, stream);

  // Occupancy-validated cooperative grid: never exceed what fits co-resident.
  int maxB = 0;
  hipOccupancyMaxActiveBlocksPerMultiprocessor(&maxB, k_lstm, 256, 0);
  int nwg = maxB * 256;
  if (nwg > NTASK) nwg = NTASK;
  if (nwg < 1) nwg = 256;

  void* args[] = { (void*)&xb, (void*)&Wt, (void*)&b0, (void*)&bL, (void*)&hbf, (void*)&out };
  hipLaunchCooperativeKernel((void*)k_lstm, dim3(nwg), dim3(256), args, 0, stream);
}

// Round 5
// 25282.384 us; speedup vs baseline: 1.6687x; 1.3118x over previous
//
#include <hip/hip_runtime.h>
#include <hip/hip_cooperative_groups.h>

#define B_ 64
#define H_ 1024
#define IN_ 512
#define S_ 256
#define L_ 6
#define NG_ 4096
#define NTASK 768            // 6 layers * 128 col-slices (8 H-cols x 4 gates)
#define NTICK (S_ + L_ - 1)

typedef __bf16 bf16x8 __attribute__((ext_vector_type(8)));
typedef float f32x4 __attribute__((ext_vector_type(4)));
typedef float f32x2 __attribute__((ext_vector_type(2)));
typedef unsigned short ushort4v __attribute__((ext_vector_type(4)));
typedef unsigned short ushort_t;

#define OFF_U0 0ul
#define OFF_V0 2097152ul
#define OFF_UL(l) (6291456ul + (unsigned long)((l) - 1) * 8388608ul)
#define OFF_VL(l) (OFF_UL(l) + 4194304ul)
#define WT_BYTES 96468992ul
#define XB_BYTES 16777216ul
#define HBF_ELEMS 786432ul    // 2*L*B*H

#define MFMA16(a, b, c) __builtin_amdgcn_mfma_f32_16x16x32_bf16(a, b, c, 0, 0, 0)
#define BAR() __builtin_amdgcn_s_barrier()
#define WAITV3() asm volatile("s_waitcnt vmcnt(3)" ::: "memory")
#define WAITV0() asm volatile("s_waitcnt vmcnt(0)" ::: "memory")

__device__ __forceinline__ unsigned short f2bf(float f) {
  union { float f; unsigned u; } v; v.f = f;
  unsigned r = v.u + 0x7fffu + ((v.u >> 16) & 1u);
  return (unsigned short)(r >> 16);
}

__device__ __forceinline__ void gload_lds(const ushort_t* g, ushort_t* l) {
  __builtin_amdgcn_global_load_lds(
      (const __attribute__((address_space(1))) unsigned int*)g,
      (__attribute__((address_space(3))) unsigned int*)l, 16, 0, 0);
}

// ---- one-time weight transpose + bf16 convert: Wt[n][k] = bf16(W[k][n]) ----
__global__ void k_transpose_bf16(const float* __restrict__ W,
                                 unsigned short* __restrict__ Wt,
                                 int K, int N) {
  __shared__ float tile[32][33];
  int n0 = blockIdx.x * 32, k0 = blockIdx.y * 32;
  int tx = threadIdx.x, ty = threadIdx.y; // 32 x 8
#pragma unroll
  for (int i = 0; i < 32; i += 8)
    tile[ty + i][tx] = W[(size_t)(k0 + ty + i) * N + (n0 + tx)];
  __syncthreads();
#pragma unroll
  for (int i = 0; i < 32; i += 8)
    Wt[(size_t)(n0 + ty + i) * K + (k0 + tx)] = f2bf(tile[tx][ty + i]);
}

// ---- one-time x -> bf16, layout [S][B][IN] ----
__global__ void k_cvt_x(const float* __restrict__ x, ushort_t* __restrict__ xb) {
  int t = blockIdx.x, b = blockIdx.y, k = threadIdx.x * 4;
  float4 v = *(const float4*)(x + ((size_t)b * S_ + t) * IN_ + k);
  ushort4v o = { f2bf(v.x), f2bf(v.y), f2bf(v.z), f2bf(v.w) };
  *(ushort4v*)(xb + ((size_t)t * B_ + b) * IN_ + k) = o;
}

__global__ void __launch_bounds__(256)
k_lstm(const ushort_t* __restrict__ xb,
       const ushort_t* __restrict__ Wt,
       const float* __restrict__ b0,
       const float* __restrict__ bL,
       ushort_t* __restrict__ hbf,   // [2][L][B][H] bf16, pre-zeroed
       float* __restrict__ out) {
  cooperative_groups::grid_group grid = cooperative_groups::this_grid();
  float* __restrict__ seq = out;                           // [B][S][H]
  float* __restrict__ hf = out + (size_t)B_ * S_ * H_;     // [L][B][H]
  float* __restrict__ cf = hf + (size_t)L_ * B_ * H_;      // [L][B][H]

  // K-chunk = 64 elements. W chunk: 32 rows x 64 = 4KB. A chunk: 64 x 64 = 8KB.
  // 3-deep ring. XOR-swizzled within each 128B row (8 x 16B units).
  __shared__ ushort_t sW[3][2048];
  __shared__ ushort_t sA[3][4096];
  __shared__ float zs[4][64][10];

  const int tid = threadIdx.x;
  const int w = tid >> 6;        // wave id: A-rows w*16..w*16+15
  const int lane = tid & 63;
  const int l15 = lane & 15;
  const int kg = lane >> 4;
  const int wg = blockIdx.x;
  const int nwg = gridDim.x;

  for (int T = 0; T < NTICK; ++T) {
    const ushort_t* __restrict__ hprev =
        hbf + (size_t)((T + 1) & 1) * (L_ * B_ * H_);
    ushort_t* __restrict__ hcur =
        hbf + (size_t)(T & 1) * (L_ * B_ * H_);

    for (int task = wg; task < NTASK; task += nwg) {
      const int l = task >> 7;
      const int jb = task & 127;
      const int t = T - l;
      if (t < 0 || t >= S_) continue;

      const int hcol0 = jb << 3;
      const int K1 = (l == 0) ? IN_ : H_;
      const int nU = K1 >> 6;
      const int nch = nU + (H_ >> 6);
      const size_t sA1 = (l == 0) ? (size_t)IN_ : (size_t)H_;
      const ushort_t* __restrict__ A1 =
          (l == 0) ? (xb + (size_t)t * (B_ * IN_))
                   : (hprev + (size_t)(l - 1) * (B_ * H_));
      const ushort_t* __restrict__ A2 = hprev + (size_t)l * (B_ * H_);
      const ushort_t* __restrict__ WU = Wt + ((l == 0) ? OFF_U0 : OFF_UL(l));
      const ushort_t* __restrict__ WV = Wt + ((l == 0) ? OFF_V0 : OFF_VL(l));

      // ---- prefetch gate-phase operands (consumed after the K loop) ----
      const int gm = tid >> 2;             // batch row 0..63
      const int gq = (tid & 3) << 1;       // col pair 0,2,4,6
      const int gcol = hcol0 + gq;
      const size_t cbase = ((size_t)l * B_ + gm) * H_ + gcol;
      const float* __restrict__ bias = (l == 0) ? b0 : (bL + (size_t)(l - 1) * NG_);
      f32x2 bi = *(const f32x2*)(bias + gcol);
      f32x2 bff = *(const f32x2*)(bias + 1024 + gcol);
      f32x2 bg = *(const f32x2*)(bias + 2048 + gcol);
      f32x2 bo = *(const f32x2*)(bias + 3072 + gcol);
      f32x2 cold = (f32x2){0.f, 0.f};
      if (t > 0) cold = *(const f32x2*)(cf + cbase);

      // ---- staging: 3 global_load_lds per wave per chunk ----
      auto stage = [&](int c) {
        const ushort_t* Ab; size_t sAs; const ushort_t* Wb; size_t Ks; int cb;
        if (c < nU) { Ab = A1; sAs = sA1; Wb = WU; Ks = (size_t)K1; cb = c << 6; }
        else        { Ab = A2; sAs = (size_t)H_; Wb = WV; Ks = (size_t)H_; cb = (c - nU) << 6; }
        const int buf = c % 3;
        {
          const int g = (w << 6) + lane;          // W unit 0..255
          const int wr = g >> 3;
          const int us = (g & 7) ^ (wr & 7);      // inverse swizzle on source
          const int ng = ((wr >> 3) << 10) + hcol0 + (wr & 7);
          gload_lds(Wb + (size_t)ng * Ks + cb + (us << 3), &sW[buf][w << 9]);
        }
#pragma unroll
        for (int i = 0; i < 2; ++i) {
          const int g = (w << 7) + (i << 6) + lane;   // A unit 0..511
          const int ar = g >> 3;
          const int us = (g & 7) ^ (ar & 7);
          gload_lds(Ab + (size_t)ar * sAs + cb + (us << 3),
                    &sA[buf][(w << 10) + (i << 9)]);
        }
      };

      stage(0);
      stage(1);

      f32x4 acc[2];
      acc[0] = (f32x4){0.f, 0.f, 0.f, 0.f};
      acc[1] = (f32x4){0.f, 0.f, 0.f, 0.f};

      for (int c = 0; c < nch; ++c) {
        // wait for chunk c (c+1 may still be in flight: 3 loads/wave)
        if (c + 1 < nch) WAITV3(); else WAITV0();
        BAR();   // publishes chunk c to all waves; retires buffer c-1 reads
        if (c + 2 < nch) stage(c + 2);

        const int buf = c % 3;
        const ushort_t* sa = sA[buf];
        const ushort_t* sw = sW[buf];
#pragma unroll
        for (int ks = 0; ks < 2; ++ks) {
          const int u = ((ks << 2) + kg) ^ (l15 & 7);
          bf16x8 av = *(const bf16x8*)(sa + ((w << 4) + l15) * 64 + (u << 3));
          bf16x8 w0 = *(const bf16x8*)(sw + l15 * 64 + (u << 3));
          bf16x8 w1 = *(const bf16x8*)(sw + (16 + l15) * 64 + (u << 3));
          acc[0] = MFMA16(av, w0, acc[0]);
          acc[1] = MFMA16(av, w1, acc[1]);
        }
      }

      // D layout: within fragment, col = l15, row = kg*4 + j
      const int g0 = l15 >> 3, c7 = l15 & 7;
#pragma unroll
      for (int nf = 0; nf < 2; ++nf)
#pragma unroll
        for (int j = 0; j < 4; ++j)
          zs[nf * 2 + g0][(w << 4) + (kg << 2) + j][c7] = acc[nf][j];
      __syncthreads();

      // ---- gate phase: 64 rows x 8 cols, 2 per thread ----
      {
        f32x2 zi = *(const f32x2*)&zs[0][gm][gq] + bi;
        f32x2 zf = *(const f32x2*)&zs[1][gm][gq] + bff;
        f32x2 zg = *(const f32x2*)&zs[2][gm][gq] + bg;
        f32x2 zo = *(const f32x2*)&zs[3][gm][gq] + bo;
        f32x2 cnew, hv;
#pragma unroll
        for (int j = 0; j < 2; ++j) {
          float iv = 1.f / (1.f + expf(-zi[j]));
          float fv = 1.f / (1.f + expf(-zf[j]));
          float gv = tanhf(zg[j]);
          float ov = 1.f / (1.f + expf(-zo[j]));
          float cn = fv * cold[j] + iv * gv;
          cnew[j] = cn;
          hv[j] = ov * tanhf(cn);
        }
        *(f32x2*)(cf + cbase) = cnew;
        *(f32x2*)(hf + cbase) = hv;
        unsigned hb2 = (unsigned)f2bf(hv[0]) | (((unsigned)f2bf(hv[1])) << 16);
        *(unsigned*)(hcur + (size_t)l * (B_ * H_) + (size_t)gm * H_ + gcol) = hb2;
        if (l == L_ - 1)
          *(f32x2*)(seq + ((size_t)gm * S_ + t) * H_ + gcol) = hv;
      }
      __syncthreads(); // zs safe before next task reuses it
    }
    grid.sync();
  }
}

extern "C" void kernel_launch(void* const* d_in, const int* in_sizes, int n_in,
                              void* d_out, int out_size, void* d_ws, size_t ws_size,
                              hipStream_t stream) {
  const float* x = (const float*)d_in[0];
  const float* U0 = (const float*)d_in[1];
  const float* V0 = (const float*)d_in[2];
  const float* b0 = (const float*)d_in[3];
  const float* U = (const float*)d_in[4];
  const float* V = (const float*)d_in[5];
  const float* bL = (const float*)d_in[6];
  float* out = (float*)d_out;

  char* ws = (char*)d_ws;
  unsigned short* Wt = (unsigned short*)ws;
  unsigned short* xb = (unsigned short*)(ws + WT_BYTES);
  unsigned short* hbf = (unsigned short*)(ws + WT_BYTES + XB_BYTES);

  dim3 tb(32, 8);
  hipLaunchKernelGGL(k_transpose_bf16, dim3(128, 16), tb, 0, stream, U0, Wt + OFF_U0, 512, 4096);
  hipLaunchKernelGGL(k_transpose_bf16, dim3(128, 32), tb, 0, stream, V0, Wt + OFF_V0, 1024, 4096);
  for (int l = 1; l < 6; ++l) {
    hipLaunchKernelGGL(k_transpose_bf16, dim3(128, 32), tb, 0, stream,
                       U + (size_t)(l - 1) * 4194304ul, Wt + OFF_UL(l), 1024, 4096);
    hipLaunchKernelGGL(k_transpose_bf16, dim3(128, 32), tb, 0, stream,
                       V + (size_t)(l - 1) * 4194304ul, Wt + OFF_VL(l), 1024, 4096);
  }
  hipLaunchKernelGGL(k_cvt_x, dim3(S_, B_), dim3(128), 0, stream, x, xb);
  hipMemsetAsync(hbf, 0, HBF_ELEMS * 2, stream);

  int maxB = 0;
  hipOccupancyMaxActiveBlocksPerMultiprocessor(&maxB, k_lstm, 256, 0);
  int nwg = maxB * 256;
  if (nwg > NTASK) nwg = NTASK;
  if (nwg < 256) nwg = 256;

  void* args[] = { (void*)&xb, (void*)&Wt, (void*)&b0, (void*)&bL, (void*)&hbf, (void*)&out };
  hipLaunchCooperativeKernel((void*)k_lstm, dim3(nwg), dim3(256), args, 0, stream);
}